// Round 1
// baseline (3269.569 us; speedup 1.0000x reference)
//
#include <hip/hip_runtime.h>
#include <math.h>

#define D 256
#define WDIM 128
#define EPSN 1e-10f

// ---------------- init: zero counters ----------------
__global__ void k_init(int* cnt) {
    if (threadIdx.x == 0) { cnt[0] = 0; cnt[1] = 0; ((float*)cnt)[2] = 0.0f; }
}

// ---------------- copy x -> new_features, compute per-row inv-norm ----------------
// wave per row: 64 lanes x float4 = 256 floats
__global__ __launch_bounds__(256) void k_copy_norm(const float* __restrict__ x,
                                                   float* __restrict__ outF,
                                                   float* __restrict__ rowinv, int N) {
    int wid = threadIdx.x >> 6, lane = threadIdx.x & 63;
    int row = blockIdx.x * 4 + wid;
    if (row >= N) return;
    float4 v = ((const float4*)(x + (size_t)row * D))[lane];
    ((float4*)(outF + (size_t)row * D))[lane] = v;
    float s = v.x * v.x + v.y * v.y + v.z * v.z + v.w * v.w;
    #pragma unroll
    for (int m = 32; m; m >>= 1) s += __shfl_xor(s, m, 64);
    if (lane == 0) rowinv[row] = 1.0f / (sqrtf(s) + EPSN);
}

// ---------------- classify tiers into compacted lists (wave-aggregated atomics) ----------------
__global__ __launch_bounds__(256) void k_classify(const int* __restrict__ tiers, int* cnt,
                                                  int* __restrict__ warm_idx,
                                                  int* __restrict__ cold_idx, int N) {
    int i = blockIdx.x * 256 + threadIdx.x;
    bool w = false, c = false;
    if (i < N) { int t = tiers[i]; w = (t == 1); c = (t == 2); }
    unsigned long long mw = __ballot(w);
    unsigned long long mc = __ballot(c);
    int lane = threadIdx.x & 63;
    unsigned long long ltmask = (lane == 0) ? 0ULL : (~0ULL >> (64 - lane));
    int pw = __popcll(mw & ltmask);
    int pc = __popcll(mc & ltmask);
    int cw = __popcll(mw), cc = __popcll(mc);
    int bw = 0, bc = 0;
    if (lane == 0) {
        if (cw) bw = atomicAdd(&cnt[0], cw);
        if (cc) bc = atomicAdd(&cnt[1], cc);
    }
    bw = __shfl(bw, 0, 64);
    bc = __shfl(bc, 0, 64);
    if (w) warm_idx[bw + pw] = i;
    if (c) cold_idx[bc + pc] = i;
}

// ---------------- normalize queries ----------------
__global__ __launch_bounds__(256) void k_qnorm(const float* __restrict__ q,
                                               float* __restrict__ qn, int B) {
    int wid = threadIdx.x >> 6, lane = threadIdx.x & 63;
    int row = blockIdx.x * 4 + wid;
    if (row >= B) return;
    float4 v = ((const float4*)(q + (size_t)row * D))[lane];
    float s = v.x * v.x + v.y * v.y + v.z * v.z + v.w * v.w;
    #pragma unroll
    for (int m = 32; m; m >>= 1) s += __shfl_xor(s, m, 64);
    float inv = 1.0f / (sqrtf(s) + EPSN);
    float4 o = make_float4(v.x * inv, v.y * inv, v.z * inv, v.w * inv);
    ((float4*)(qn + (size_t)row * D))[lane] = o;
}

// ---------------- warm rows: mu/logvar GEMV, kl, dec GEMV, write new_features ----------------
// 32 warm rows per block, 256 threads
__global__ __launch_bounds__(256) void k_warm(const float* __restrict__ x,
                                              const float* __restrict__ Wmu, const float* __restrict__ bmu,
                                              const float* __restrict__ Wlv, const float* __restrict__ blv,
                                              const float* __restrict__ Wdec, const float* __restrict__ bdec,
                                              const int* __restrict__ warm_idx, const int* cnt,
                                              float* __restrict__ outF, float* klacc) {
    __shared__ float xs[32][260];   // +4 pad: bank-spread for 16B reads
    __shared__ float mus[32][132];
    __shared__ float klbuf[4];
    int nw = cnt[0];
    int base = blockIdx.x * 32;
    if (base >= nw) return;
    int m = min(32, nw - base);
    int tid = threadIdx.x;
    // stage X tile (gathered rows)
    for (int i = tid; i < 32 * 64; i += 256) {
        int r = i >> 6, c4 = i & 63;
        float4 v = make_float4(0.f, 0.f, 0.f, 0.f);
        if (r < m) v = ((const float4*)(x + (size_t)warm_idx[base + r] * D))[c4];
        *(float4*)&xs[r][c4 * 4] = v;
    }
    __syncthreads();
    // mu / logvar: thread = 4 rows x 4 w-cols
    int wg = tid & 31, rg = tid >> 5;
    int w0 = wg * 4, r0 = rg * 4;
    float amu[4][4] = {{0}}, alv[4][4] = {{0}};
    for (int k4 = 0; k4 < 64; ++k4) {
        float4 xv[4];
        #pragma unroll
        for (int i = 0; i < 4; ++i) xv[i] = *(const float4*)&xs[r0 + i][k4 * 4];
        #pragma unroll
        for (int j = 0; j < 4; ++j) {
            float4 wm = ((const float4*)(Wmu + (size_t)(w0 + j) * D))[k4];
            float4 wl = ((const float4*)(Wlv + (size_t)(w0 + j) * D))[k4];
            #pragma unroll
            for (int i = 0; i < 4; ++i) {
                amu[i][j] += xv[i].x * wm.x + xv[i].y * wm.y + xv[i].z * wm.z + xv[i].w * wm.w;
                alv[i][j] += xv[i].x * wl.x + xv[i].y * wl.y + xv[i].z * wl.z + xv[i].w * wl.w;
            }
        }
    }
    float kll = 0.0f;
    #pragma unroll
    for (int i = 0; i < 4; ++i) {
        #pragma unroll
        for (int j = 0; j < 4; ++j) {
            float mu = amu[i][j] + bmu[w0 + j];
            float lv = alv[i][j] + blv[w0 + j];
            mus[r0 + i][w0 + j] = mu;
            if (r0 + i < m) kll += -0.5f * (1.0f + lv - mu * mu - __expf(lv));
        }
    }
    #pragma unroll
    for (int s = 32; s; s >>= 1) kll += __shfl_xor(kll, s, 64);
    if ((tid & 63) == 0) klbuf[tid >> 6] = kll;
    __syncthreads();  // mus visible + klbuf ready
    if (tid == 0) atomicAdd(klacc, klbuf[0] + klbuf[1] + klbuf[2] + klbuf[3]);
    // dec: thread = 8 rows x 4 d-cols
    int cg = tid & 63, rg2 = tid >> 6;
    int c0 = cg * 4, rr0 = rg2 * 8;
    float ad[8][4] = {{0}};
    for (int k4 = 0; k4 < 32; ++k4) {
        float4 mv[8];
        #pragma unroll
        for (int i = 0; i < 8; ++i) mv[i] = *(const float4*)&mus[rr0 + i][k4 * 4];
        #pragma unroll
        for (int j = 0; j < 4; ++j) {
            float4 wd = ((const float4*)(Wdec + (size_t)(c0 + j) * WDIM))[k4];
            #pragma unroll
            for (int i = 0; i < 8; ++i)
                ad[i][j] += mv[i].x * wd.x + mv[i].y * wd.y + mv[i].z * wd.z + mv[i].w * wd.w;
        }
    }
    #pragma unroll
    for (int i = 0; i < 8; ++i) {
        int r = rr0 + i;
        if (r < m) {
            int rowg = warm_idx[base + r];
            float4 o;
            o.x = ad[i][0] + bdec[c0 + 0];
            o.y = ad[i][1] + bdec[c0 + 1];
            o.z = ad[i][2] + bdec[c0 + 2];
            o.w = ad[i][3] + bdec[c0 + 3];
            *(float4*)(outF + (size_t)rowg * D + c0) = o;
        }
    }
}

// ---------------- sim for cold rows: simC[q][coldpos] ----------------
// 64 cold rows per block, 256 threads = 16 q-groups x 16 row-groups (4x4 each)
__global__ __launch_bounds__(256) void k_sim(const float* __restrict__ x,
                                             const float* __restrict__ qn,
                                             const int* __restrict__ cold_idx,
                                             const float* __restrict__ rowinv, const int* cnt,
                                             float* __restrict__ simC) {
    __shared__ float xs[64][256];  // 64 KB
    int nc = cnt[1];
    int base = blockIdx.x * 64;
    if (base >= nc) return;
    int m = min(64, nc - base);
    int tid = threadIdx.x;
    for (int i = tid; i < 64 * 64; i += 256) {
        int r = i >> 6, c4 = i & 63;
        float4 v = make_float4(0.f, 0.f, 0.f, 0.f);
        if (r < m) v = ((const float4*)(x + (size_t)cold_idx[base + r] * D))[c4];
        *(float4*)&xs[r][c4 * 4] = v;
    }
    __syncthreads();
    int qg = tid & 15, rg = tid >> 4;
    int q0 = qg * 4, r0 = rg * 4;
    float acc[4][4] = {{0}};
    for (int k4 = 0; k4 < 64; ++k4) {
        float4 xv[4];
        #pragma unroll
        for (int i = 0; i < 4; ++i) xv[i] = *(const float4*)&xs[r0 + i][k4 * 4];
        #pragma unroll
        for (int j = 0; j < 4; ++j) {
            float4 qv = ((const float4*)(qn + (size_t)(q0 + j) * D))[k4];
            #pragma unroll
            for (int i = 0; i < 4; ++i)
                acc[i][j] += xv[i].x * qv.x + xv[i].y * qv.y + xv[i].z * qv.z + xv[i].w * qv.w;
        }
    }
    #pragma unroll
    for (int i = 0; i < 4; ++i) {
        int r = r0 + i;
        if (r < m) {
            float inv = rowinv[cold_idx[base + r]];
            #pragma unroll
            for (int j = 0; j < 4; ++j)
                simC[(size_t)(q0 + j) * nc + base + r] = acc[i][j] * inv;
        }
    }
}

// ---------------- top-k (k=16) per query + gather retrieved + write idx ----------------
__global__ __launch_bounds__(256) void k_topk(const float* __restrict__ simC,
                                              const int* __restrict__ cold_idx, const int* cnt,
                                              const float* __restrict__ newF,
                                              float* __restrict__ outRetr,
                                              float* __restrict__ outIdx) {
    __shared__ float sv[256 * 16];
    __shared__ int si[256 * 16];
    int q = blockIdx.x, tid = threadIdx.x;
    int nc = cnt[1];
    float lv[16]; int li[16];
    #pragma unroll
    for (int t = 0; t < 16; ++t) { lv[t] = -3.0e38f; li[t] = 0x7fffffff; }
    for (int j = tid; j < nc; j += 256) {
        float v = simC[(size_t)q * nc + j];
        int gi = cold_idx[j];
        // better-than-current-min? (tie: lower index wins)
        if (v > lv[0] || (v == lv[0] && gi < li[0])) {
            lv[0] = v; li[0] = gi;
            #pragma unroll
            for (int t = 0; t < 15; ++t) {
                bool sw = (lv[t] > lv[t + 1]) || (lv[t] == lv[t + 1] && li[t] < li[t + 1]);
                float tv = sw ? lv[t + 1] : lv[t];
                float uv = sw ? lv[t] : lv[t + 1];
                int ti = sw ? li[t + 1] : li[t];
                int ui = sw ? li[t] : li[t + 1];
                lv[t] = tv; lv[t + 1] = uv; li[t] = ti; li[t + 1] = ui;
            }
        }
    }
    // dump descending
    #pragma unroll
    for (int t = 0; t < 16; ++t) { sv[tid * 16 + t] = lv[15 - t]; si[tid * 16 + t] = li[15 - t]; }
    __syncthreads();
    for (int off = 128; off >= 1; off >>= 1) {
        if (tid < off) {
            int a = tid * 16, b = (tid + off) * 16;
            float ov[16]; int oi[16];
            int i = 0, j = 0;
            #pragma unroll
            for (int t = 0; t < 16; ++t) {
                float avv = sv[a + i], bvv = sv[b + j];
                int aii = si[a + i], bii = si[b + j];
                bool ta = (avv > bvv) || (avv == bvv && aii < bii);
                ov[t] = ta ? avv : bvv;
                oi[t] = ta ? aii : bii;
                i += ta ? 1 : 0;
                j += ta ? 0 : 1;
            }
            #pragma unroll
            for (int t = 0; t < 16; ++t) { sv[a + t] = ov[t]; si[a + t] = oi[t]; }
        }
        __syncthreads();
    }
    if (tid < 16) outIdx[q * 16 + tid] = (float)si[tid];
    for (int i = tid; i < 16 * D; i += 256) {
        int r = i >> 8, c = i & 255;
        outRetr[(size_t)q * 16 * D + i] = newF[(size_t)si[r] * D + c];
    }
}

// ---------------- kl finalize ----------------
__global__ void k_klfin(const int* cnt, float* outKl, int Wk) {
    float kl = ((const float*)cnt)[2];
    int nw = cnt[0]; if (nw < 1) nw = 1;
    *outKl = kl / ((float)nw * (float)Wk);
}

extern "C" void kernel_launch(void* const* d_in, const int* in_sizes, int n_in,
                              void* d_out, int out_size, void* d_ws, size_t ws_size,
                              hipStream_t stream) {
    (void)n_in; (void)out_size; (void)ws_size;
    const float* x    = (const float*)d_in[0];
    const int*   tier = (const int*)d_in[1];
    const float* qry  = (const float*)d_in[2];
    const float* Wmu  = (const float*)d_in[3];
    const float* bmu  = (const float*)d_in[4];
    const float* Wlv  = (const float*)d_in[5];
    const float* blv  = (const float*)d_in[6];
    const float* Wdec = (const float*)d_in[7];
    const float* bdec = (const float*)d_in[8];
    int N = in_sizes[0] / D;   // 200000
    int B = in_sizes[2] / D;   // 64
    int Wk = in_sizes[4];      // 128

    float* outF    = (float*)d_out;
    float* outKl   = outF + (size_t)N * D;
    float* outRetr = outKl + 1;
    float* outIdx  = outRetr + (size_t)B * 16 * D;

    char* ws = (char*)d_ws;
    int*   cnt      = (int*)ws;                       // [warm, cold, klacc(float)]
    int*   warm_idx = (int*)(ws + 256);
    int*   cold_idx = warm_idx + N;
    float* rowinv   = (float*)(cold_idx + N);
    float* qn       = rowinv + N;
    float* simC     = qn + (size_t)B * D;             // B * cold_count floats

    k_init<<<1, 64, 0, stream>>>(cnt);
    k_copy_norm<<<(N + 3) / 4, 256, 0, stream>>>(x, outF, rowinv, N);
    k_classify<<<(N + 255) / 256, 256, 0, stream>>>(tier, cnt, warm_idx, cold_idx, N);
    k_qnorm<<<(B + 3) / 4, 256, 0, stream>>>(qry, qn, B);
    k_warm<<<(N + 31) / 32, 256, 0, stream>>>(x, Wmu, bmu, Wlv, blv, Wdec, bdec,
                                              warm_idx, cnt, outF, (float*)cnt + 2);
    k_sim<<<(N + 63) / 64, 256, 0, stream>>>(x, qn, cold_idx, rowinv, cnt, simC);
    k_topk<<<B, 256, 0, stream>>>(simC, cold_idx, cnt, outF, outRetr, outIdx);
    k_klfin<<<1, 1, 0, stream>>>(cnt, outKl, Wk);
}

// Round 2
// 1409.900 us; speedup vs baseline: 2.3190x; 2.3190x over previous
//
#include <hip/hip_runtime.h>
#include <math.h>

#define D 256
#define WDIM 128
#define EPSN 1e-10f
#define CHUNK 2048
#define C2 2048

// ---------------- init: zero counters ----------------
__global__ void k_init(int* cnt) {
    if (threadIdx.x == 0) { cnt[0] = 0; cnt[1] = 0; ((float*)cnt)[2] = 0.0f; }
}

// ---------------- copy x -> new_features, compute per-row inv-norm ----------------
__global__ __launch_bounds__(256) void k_copy_norm(const float* __restrict__ x,
                                                   float* __restrict__ outF,
                                                   float* __restrict__ rowinv, int N) {
    int wid = threadIdx.x >> 6, lane = threadIdx.x & 63;
    int row = blockIdx.x * 4 + wid;
    if (row >= N) return;
    float4 v = ((const float4*)(x + (size_t)row * D))[lane];
    ((float4*)(outF + (size_t)row * D))[lane] = v;
    float s = v.x * v.x + v.y * v.y + v.z * v.z + v.w * v.w;
    #pragma unroll
    for (int m = 32; m; m >>= 1) s += __shfl_xor(s, m, 64);
    if (lane == 0) rowinv[row] = 1.0f / (sqrtf(s) + EPSN);
}

// ---------------- classify tiers into compacted lists ----------------
__global__ __launch_bounds__(256) void k_classify(const int* __restrict__ tiers, int* cnt,
                                                  int* __restrict__ warm_idx,
                                                  int* __restrict__ cold_idx, int N) {
    int i = blockIdx.x * 256 + threadIdx.x;
    bool w = false, c = false;
    if (i < N) { int t = tiers[i]; w = (t == 1); c = (t == 2); }
    unsigned long long mw = __ballot(w);
    unsigned long long mc = __ballot(c);
    int lane = threadIdx.x & 63;
    unsigned long long ltmask = (lane == 0) ? 0ULL : (~0ULL >> (64 - lane));
    int pw = __popcll(mw & ltmask);
    int pc = __popcll(mc & ltmask);
    int cw = __popcll(mw), cc = __popcll(mc);
    int bw = 0, bc = 0;
    if (lane == 0) {
        if (cw) bw = atomicAdd(&cnt[0], cw);
        if (cc) bc = atomicAdd(&cnt[1], cc);
    }
    bw = __shfl(bw, 0, 64);
    bc = __shfl(bc, 0, 64);
    if (w) warm_idx[bw + pw] = i;
    if (c) cold_idx[bc + pc] = i;
}

// ---------------- normalize queries ----------------
__global__ __launch_bounds__(256) void k_qnorm(const float* __restrict__ q,
                                               float* __restrict__ qn, int B) {
    int wid = threadIdx.x >> 6, lane = threadIdx.x & 63;
    int row = blockIdx.x * 4 + wid;
    if (row >= B) return;
    float4 v = ((const float4*)(q + (size_t)row * D))[lane];
    float s = v.x * v.x + v.y * v.y + v.z * v.z + v.w * v.w;
    #pragma unroll
    for (int m = 32; m; m >>= 1) s += __shfl_xor(s, m, 64);
    float inv = 1.0f / (sqrtf(s) + EPSN);
    float4 o = make_float4(v.x * inv, v.y * inv, v.z * inv, v.w * inv);
    ((float4*)(qn + (size_t)row * D))[lane] = o;
}

// ---------------- warm rows: mu/logvar GEMV, kl, dec GEMV ----------------
__global__ __launch_bounds__(256) void k_warm(const float* __restrict__ x,
                                              const float* __restrict__ Wmu, const float* __restrict__ bmu,
                                              const float* __restrict__ Wlv, const float* __restrict__ blv,
                                              const float* __restrict__ Wdec, const float* __restrict__ bdec,
                                              const int* __restrict__ warm_idx, const int* cnt,
                                              float* __restrict__ outF, float* klacc) {
    __shared__ float xs[32][260];
    __shared__ float mus[32][132];
    __shared__ float klbuf[4];
    int nw = cnt[0];
    int base = blockIdx.x * 32;
    if (base >= nw) return;
    int m = min(32, nw - base);
    int tid = threadIdx.x;
    for (int i = tid; i < 32 * 64; i += 256) {
        int r = i >> 6, c4 = i & 63;
        float4 v = make_float4(0.f, 0.f, 0.f, 0.f);
        if (r < m) v = ((const float4*)(x + (size_t)warm_idx[base + r] * D))[c4];
        *(float4*)&xs[r][c4 * 4] = v;
    }
    __syncthreads();
    int wg = tid & 31, rg = tid >> 5;
    int w0 = wg * 4, r0 = rg * 4;
    float amu[4][4] = {{0}}, alv[4][4] = {{0}};
    for (int k4 = 0; k4 < 64; ++k4) {
        float4 xv[4];
        #pragma unroll
        for (int i = 0; i < 4; ++i) xv[i] = *(const float4*)&xs[r0 + i][k4 * 4];
        #pragma unroll
        for (int j = 0; j < 4; ++j) {
            float4 wm = ((const float4*)(Wmu + (size_t)(w0 + j) * D))[k4];
            float4 wl = ((const float4*)(Wlv + (size_t)(w0 + j) * D))[k4];
            #pragma unroll
            for (int i = 0; i < 4; ++i) {
                amu[i][j] += xv[i].x * wm.x + xv[i].y * wm.y + xv[i].z * wm.z + xv[i].w * wm.w;
                alv[i][j] += xv[i].x * wl.x + xv[i].y * wl.y + xv[i].z * wl.z + xv[i].w * wl.w;
            }
        }
    }
    float kll = 0.0f;
    #pragma unroll
    for (int i = 0; i < 4; ++i) {
        #pragma unroll
        for (int j = 0; j < 4; ++j) {
            float mu = amu[i][j] + bmu[w0 + j];
            float lv = alv[i][j] + blv[w0 + j];
            mus[r0 + i][w0 + j] = mu;
            if (r0 + i < m) kll += -0.5f * (1.0f + lv - mu * mu - __expf(lv));
        }
    }
    #pragma unroll
    for (int s = 32; s; s >>= 1) kll += __shfl_xor(kll, s, 64);
    if ((tid & 63) == 0) klbuf[tid >> 6] = kll;
    __syncthreads();
    if (tid == 0) atomicAdd(klacc, klbuf[0] + klbuf[1] + klbuf[2] + klbuf[3]);
    int cg = tid & 63, rg2 = tid >> 6;
    int c0 = cg * 4, rr0 = rg2 * 8;
    float ad[8][4] = {{0}};
    for (int k4 = 0; k4 < 32; ++k4) {
        float4 mv[8];
        #pragma unroll
        for (int i = 0; i < 8; ++i) mv[i] = *(const float4*)&mus[rr0 + i][k4 * 4];
        #pragma unroll
        for (int j = 0; j < 4; ++j) {
            float4 wd = ((const float4*)(Wdec + (size_t)(c0 + j) * WDIM))[k4];
            #pragma unroll
            for (int i = 0; i < 8; ++i)
                ad[i][j] += mv[i].x * wd.x + mv[i].y * wd.y + mv[i].z * wd.z + mv[i].w * wd.w;
        }
    }
    #pragma unroll
    for (int i = 0; i < 8; ++i) {
        int r = rr0 + i;
        if (r < m) {
            int rowg = warm_idx[base + r];
            float4 o;
            o.x = ad[i][0] + bdec[c0 + 0];
            o.y = ad[i][1] + bdec[c0 + 1];
            o.z = ad[i][2] + bdec[c0 + 2];
            o.w = ad[i][3] + bdec[c0 + 3];
            *(float4*)(outF + (size_t)rowg * D + c0) = o;
        }
    }
}

// ---------------- sim for cold rows ----------------
__global__ __launch_bounds__(256) void k_sim(const float* __restrict__ x,
                                             const float* __restrict__ qn,
                                             const int* __restrict__ cold_idx,
                                             const float* __restrict__ rowinv, const int* cnt,
                                             float* __restrict__ simC) {
    __shared__ float xs[64][256];
    int nc = cnt[1];
    int base = blockIdx.x * 64;
    if (base >= nc) return;
    int m = min(64, nc - base);
    int tid = threadIdx.x;
    for (int i = tid; i < 64 * 64; i += 256) {
        int r = i >> 6, c4 = i & 63;
        float4 v = make_float4(0.f, 0.f, 0.f, 0.f);
        if (r < m) v = ((const float4*)(x + (size_t)cold_idx[base + r] * D))[c4];
        *(float4*)&xs[r][c4 * 4] = v;
    }
    __syncthreads();
    int qg = tid & 15, rg = tid >> 4;
    int q0 = qg * 4, r0 = rg * 4;
    float acc[4][4] = {{0}};
    for (int k4 = 0; k4 < 64; ++k4) {
        float4 xv[4];
        #pragma unroll
        for (int i = 0; i < 4; ++i) xv[i] = *(const float4*)&xs[r0 + i][k4 * 4];
        #pragma unroll
        for (int j = 0; j < 4; ++j) {
            float4 qv = ((const float4*)(qn + (size_t)(q0 + j) * D))[k4];
            #pragma unroll
            for (int i = 0; i < 4; ++i)
                acc[i][j] += xv[i].x * qv.x + xv[i].y * qv.y + xv[i].z * qv.z + xv[i].w * qv.w;
        }
    }
    #pragma unroll
    for (int i = 0; i < 4; ++i) {
        int r = r0 + i;
        if (r < m) {
            float inv = rowinv[cold_idx[base + r]];
            #pragma unroll
            for (int j = 0; j < 4; ++j)
                simC[(size_t)(q0 + j) * nc + base + r] = acc[i][j] * inv;
        }
    }
}

// ---------------- top-k phase 1: per-(query,chunk) top-16 as u64 keys ----------------
__device__ __forceinline__ unsigned long long mkkey(float v, int gi) {
    unsigned int b = __float_as_uint(v);
    b = (b & 0x80000000u) ? ~b : (b | 0x80000000u);
    return ((unsigned long long)b << 32) | (unsigned int)(~gi);
}

#define CE(a, b) { unsigned long long _hi = (a) >= (b) ? (a) : (b); \
                   unsigned long long _lo = (a) >= (b) ? (b) : (a); \
                   (a) = _hi; (b) = _lo; }

__global__ __launch_bounds__(256) void k_top1(const float* __restrict__ simC,
                                              const int* __restrict__ cold_idx,
                                              const int* cnt, int Mmax,
                                              unsigned long long* __restrict__ cand) {
    __shared__ unsigned long long P0[256 * 17];
    __shared__ unsigned long long P1[128 * 17];
    int nc = cnt[1];
    int c = blockIdx.x, q = blockIdx.y;
    int base = c * CHUNK;
    if (base >= nc) return;
    int tid = threadIdx.x;
    const float* srow = simC + (size_t)q * nc;
    #define LOADK(s) ((base + tid + (s)*256 < nc) \
        ? mkkey(srow[base + tid + (s)*256], cold_idx[base + tid + (s)*256]) : 0ULL)
    unsigned long long k0 = LOADK(0), k1 = LOADK(1), k2 = LOADK(2), k3 = LOADK(3);
    unsigned long long k4 = LOADK(4), k5 = LOADK(5), k6 = LOADK(6), k7 = LOADK(7);
    #undef LOADK
    // Batcher odd-even mergesort of 8 (descending), explicit scalars -> registers
    CE(k0,k1) CE(k2,k3) CE(k4,k5) CE(k6,k7)
    CE(k0,k2) CE(k1,k3) CE(k4,k6) CE(k5,k7)
    CE(k1,k2) CE(k5,k6)
    CE(k0,k4) CE(k1,k5) CE(k2,k6) CE(k3,k7)
    CE(k2,k4) CE(k3,k5)
    CE(k1,k2) CE(k3,k4) CE(k5,k6)
    unsigned long long* L = P0 + tid * 17;
    L[0]=k0; L[1]=k1; L[2]=k2; L[3]=k3; L[4]=k4; L[5]=k5; L[6]=k6; L[7]=k7;
    L[8]=0; L[9]=0; L[10]=0; L[11]=0; L[12]=0; L[13]=0; L[14]=0; L[15]=0;
    __syncthreads();
    // merge tree, ping-pong (no per-thread output arrays)
    unsigned long long* src = P0;
    unsigned long long* dst = P1;
    int nl = 256;
    while (nl > 1) {
        int half = nl >> 1;
        if (tid < half) {
            unsigned long long* A  = src + (2 * tid) * 17;
            unsigned long long* Bp = src + (2 * tid + 1) * 17;
            unsigned long long* O  = dst + tid * 17;
            int i = 0, j = 0;
            #pragma unroll
            for (int t = 0; t < 16; ++t) {
                unsigned long long ka = A[i], kb = Bp[j];
                bool ta = ka >= kb;
                O[t] = ta ? ka : kb;
                i += ta ? 1 : 0;
                j += ta ? 0 : 1;
            }
        }
        __syncthreads();
        unsigned long long* tmp = src; src = dst; dst = tmp;
        nl = half;
    }
    if (tid < 16) cand[((size_t)q * Mmax + c) * 16 + tid] = src[tid];
}

// ---------------- top-k phase 2: bitonic merge of candidates + gather ----------------
__global__ __launch_bounds__(256) void k_top2(const unsigned long long* __restrict__ cand,
                                              const int* cnt, int Mmax,
                                              const float* __restrict__ newF,
                                              float* __restrict__ outRetr,
                                              float* __restrict__ outIdx) {
    __shared__ unsigned long long K[C2];
    int q = blockIdx.x, tid = threadIdx.x;
    int nc = cnt[1];
    int M = (nc + CHUNK - 1) / CHUNK; if (M > Mmax) M = Mmax;
    int C = M * 16;
    for (int i = tid; i < C2; i += 256)
        K[i] = (i < C) ? cand[(size_t)q * Mmax * 16 + i] : 0ULL;
    __syncthreads();
    for (int kk = 2; kk <= C2; kk <<= 1) {
        for (int jj = kk >> 1; jj > 0; jj >>= 1) {
            for (int idx = tid; idx < C2; idx += 256) {
                int p = idx ^ jj;
                if (p > idx) {
                    bool dirDesc = ((idx & kk) == 0);
                    unsigned long long a = K[idx], b = K[p];
                    bool sw = dirDesc ? (a < b) : (a > b);
                    if (sw) { K[idx] = b; K[p] = a; }
                }
            }
            __syncthreads();
        }
    }
    if (tid < 16) {
        int gi = (int)(~(unsigned int)(K[tid] & 0xffffffffULL));
        outIdx[q * 16 + tid] = (float)gi;
    }
    for (int i = tid; i < 16 * D; i += 256) {
        int r = i >> 8, cc = i & 255;
        int gi = (int)(~(unsigned int)(K[r] & 0xffffffffULL));
        outRetr[(size_t)q * 16 * D + i] = newF[(size_t)gi * D + cc];
    }
}

// ---------------- kl finalize ----------------
__global__ void k_klfin(const int* cnt, float* outKl, int Wk) {
    float kl = ((const float*)cnt)[2];
    int nw = cnt[0]; if (nw < 1) nw = 1;
    *outKl = kl / ((float)nw * (float)Wk);
}

extern "C" void kernel_launch(void* const* d_in, const int* in_sizes, int n_in,
                              void* d_out, int out_size, void* d_ws, size_t ws_size,
                              hipStream_t stream) {
    (void)n_in; (void)out_size; (void)ws_size;
    const float* x    = (const float*)d_in[0];
    const int*   tier = (const int*)d_in[1];
    const float* qry  = (const float*)d_in[2];
    const float* Wmu  = (const float*)d_in[3];
    const float* bmu  = (const float*)d_in[4];
    const float* Wlv  = (const float*)d_in[5];
    const float* blv  = (const float*)d_in[6];
    const float* Wdec = (const float*)d_in[7];
    const float* bdec = (const float*)d_in[8];
    int N = in_sizes[0] / D;   // 200000
    int B = in_sizes[2] / D;   // 64
    int Wk = in_sizes[4];      // 128
    int Mmax = (N + CHUNK - 1) / CHUNK;  // 98

    float* outF    = (float*)d_out;
    float* outKl   = outF + (size_t)N * D;
    float* outRetr = outKl + 1;
    float* outIdx  = outRetr + (size_t)B * 16 * D;

    char* ws = (char*)d_ws;
    int*   cnt      = (int*)ws;                       // [warm, cold, klacc(float)]
    int*   warm_idx = (int*)(ws + 256);
    int*   cold_idx = warm_idx + N;
    float* rowinv   = (float*)(cold_idx + N);
    float* qn       = rowinv + N;
    unsigned long long* cand = (unsigned long long*)(qn + (size_t)B * D); // 8-aligned
    float* simC     = (float*)(cand + (size_t)B * Mmax * 16);

    k_init<<<1, 64, 0, stream>>>(cnt);
    k_copy_norm<<<(N + 3) / 4, 256, 0, stream>>>(x, outF, rowinv, N);
    k_classify<<<(N + 255) / 256, 256, 0, stream>>>(tier, cnt, warm_idx, cold_idx, N);
    k_qnorm<<<(B + 3) / 4, 256, 0, stream>>>(qry, qn, B);
    k_warm<<<(N + 31) / 32, 256, 0, stream>>>(x, Wmu, bmu, Wlv, blv, Wdec, bdec,
                                              warm_idx, cnt, outF, (float*)cnt + 2);
    k_sim<<<(N + 63) / 64, 256, 0, stream>>>(x, qn, cold_idx, rowinv, cnt, simC);
    k_top1<<<dim3(Mmax, B), 256, 0, stream>>>(simC, cold_idx, cnt, Mmax, cand);
    k_top2<<<B, 256, 0, stream>>>(cand, cnt, Mmax, outF, outRetr, outIdx);
    k_klfin<<<1, 1, 0, stream>>>(cnt, outKl, Wk);
}